// Round 16
// baseline (136.035 us; speedup 1.0000x reference)
//
#include <hip/hip_runtime.h>

// SparseLinear: out[b, j] = sum_{e: dst[e]==j} values[e] * x[b, src[e]] + bias[j]
// Inputs: x f32 (B,N_IN,1) | values f32 (NNZ,) | bias f32 (N_OUT,1)
//         indices i32 (2,NNZ) row0=src row1=dst | n_out scalar
// Output: f32 (B, N_OUT, 1)
//
// Round-16: stage-less partition. Records stay in registers; LDS holds only
// scount+sbase (12.8 KB vs 108.8 KB) -> 3-4 blocks/CU (was 1). Slot claim via
// LDS atomic, one cur-atomic per touched bucket, then each OWNING thread
// stores its records (8 independent stores vs serialized flush). CAP=32 is
// now free (counter threshold only) -> single round per batch. L2 merges the
// line-clustered 8B stores. Gather/fixup = round-15.

#define TJ 64
#define TJ_LOG 6
#define PACK_SHIFT 17          // src in bits [0,17), jl=dst&63 in [17,23)
#define SRC_MASK ((1u << PACK_SHIFT) - 1u)
#define NSB_MAX 1600
#define CAP 32                 // slot threshold per bucket per round (free now)
#define A1_THREADS 512
#define A1_PER_THREAD 8
#define A1_BATCH (A1_THREADS * A1_PER_THREAD)   // 4096
#define CHUNK 2048             // gather records per LDS chunk
#define GT 512                 // gather threads (8 waves)
#define OVF_CAP 65536          // overflow records (1 MB)

__device__ __forceinline__ unsigned short f32_to_bf16_rn(float f) {
    unsigned u = __float_as_uint(f);
    unsigned r = (u + 0x7FFFu + ((u >> 16) & 1u)) >> 16;
    return (unsigned short)r;
}

// ---------- transpose x (B=32, N) -> xTh (N, 32) bf16 ----------
__global__ void xpose_in_kernel(const float* __restrict__ x, unsigned short* __restrict__ xTh,
                                int N) {
    __shared__ float tile[32][33];
    int n0 = blockIdx.x * 32;
    int tx = threadIdx.x;
    int ty = threadIdx.y;
    if (n0 + tx < N) tile[ty][tx] = x[ty * (long)N + n0 + tx];
    __syncthreads();
    if (n0 + ty < N) xTh[(long)(n0 + ty) * 32 + tx] = f32_to_bf16_rn(tile[tx][ty]);
}

// ---------- init cursors: cur[c] = c*caps; ovf_cnt = 0 ----------
__global__ void init_cur_kernel(int* __restrict__ cur, int* __restrict__ ovf_cnt,
                                int nsb, int caps) {
    int i = blockIdx.x * blockDim.x + threadIdx.x;
    if (i < nsb) cur[i] = i * caps;
    if (i == 0) *ovf_cnt = 0;
}

// ---------- partition: stage-less, records in registers, owner-stores ----------
__global__ __launch_bounds__(A1_THREADS) void partition_kernel(
        const int* __restrict__ src, const int* __restrict__ dst,
        const float* __restrict__ val, int* __restrict__ cur,
        uint2* __restrict__ binA, uint4* __restrict__ ovf, int* __restrict__ ovf_cnt,
        int nnz, int nsb, int caps) {
    __shared__ int scount[NSB_MAX];   // 6.4 KB
    __shared__ int sbase[NSB_MAX];    // 6.4 KB
    for (int i = threadIdx.x; i < nsb; i += A1_THREADS) scount[i] = 0;
    __syncthreads();

    for (long base = (long)blockIdx.x * A1_BATCH; base < nnz;
         base += (long)gridDim.x * A1_BATCH) {
        uint2 rec[A1_PER_THREAD];
        int bkt[A1_PER_THREAD];
        int st[A1_PER_THREAD];       // -2 none/done, -1 pending, >=0 slot this round
#pragma unroll
        for (int q = 0; q < A1_PER_THREAD; ++q) st[q] = -2;

        int e0 = (int)base + threadIdx.x * A1_PER_THREAD;
        if (e0 < nnz) {
            if (e0 + A1_PER_THREAD <= nnz) {
                const int4* s4 = (const int4*)(src + e0);
                const int4* d4 = (const int4*)(dst + e0);
                const float4* v4 = (const float4*)(val + e0);
                int4 sa = s4[0], sb = s4[1];
                int4 da = d4[0], db = d4[1];
                float4 va = v4[0], vb = v4[1];
                int ss[8] = {sa.x, sa.y, sa.z, sa.w, sb.x, sb.y, sb.z, sb.w};
                int dd[8] = {da.x, da.y, da.z, da.w, db.x, db.y, db.z, db.w};
                float vv[8] = {va.x, va.y, va.z, va.w, vb.x, vb.y, vb.z, vb.w};
#pragma unroll
                for (int q = 0; q < 8; ++q) {
                    rec[q] = make_uint2((unsigned)ss[q] | ((unsigned)(dd[q] & (TJ - 1)) << PACK_SHIFT),
                                        __float_as_uint(vv[q]));
                    bkt[q] = dd[q] >> TJ_LOG;
                    st[q] = -1;
                }
            } else {
#pragma unroll
                for (int q = 0; q < 8; ++q) {
                    int e = e0 + q;
                    if (e < nnz) {
                        int d = dst[e];
                        rec[q] = make_uint2((unsigned)src[e] | ((unsigned)(d & (TJ - 1)) << PACK_SHIFT),
                                            __float_as_uint(val[e]));
                        bkt[q] = d >> TJ_LOG;
                        st[q] = -1;
                    }
                }
            }
        }

        while (true) {
            // A) claim slots (records stay in registers)
#pragma unroll
            for (int q = 0; q < A1_PER_THREAD; ++q) {
                if (st[q] == -1) {
                    int s = atomicAdd(&scount[bkt[q]], 1);
                    if (s < CAP) st[q] = s;
                }
            }
            __syncthreads();
            // B) publish global bases, one cur-atomic per touched bucket; reset scount
            for (int t = threadIdx.x; t < nsb; t += A1_THREADS) {
                int cc = scount[t];
                if (cc > 0) {
                    if (cc > CAP) cc = CAP;
                    sbase[t] = atomicAdd(&cur[t], cc);
                    scount[t] = 0;
                }
            }
            __syncthreads();
            // C) owner stores; per-record capacity check spills to ovf
            int rem = 0;
#pragma unroll
            for (int q = 0; q < A1_PER_THREAD; ++q) {
                if (st[q] >= 0) {
                    int g = sbase[bkt[q]] + st[q];
                    if (g < (bkt[q] + 1) * caps) {
                        binA[g] = rec[q];
                    } else {
                        int ob = atomicAdd(ovf_cnt, 1);
                        if (ob < OVF_CAP) {
                            ovf[ob] = make_uint4(rec[q].x & SRC_MASK,
                                                 (unsigned)(bkt[q] * TJ) + (rec[q].x >> PACK_SHIFT),
                                                 rec[q].y, 0u);
                        }
                    }
                    st[q] = -2;
                } else if (st[q] == -1) {
                    ++rem;   // failed slot claim (scount raced past CAP) -> retry
                }
            }
            if (__syncthreads_count(rem) == 0) break;
        }
    }
}

// ---------- gather_sort: per-wave hist + disjoint scatter + 4-edge/instr walk ----------
__global__ __launch_bounds__(GT) void gather_sort_kernel(
        const uint2* __restrict__ binA, const int* __restrict__ cur, int caps,
        const unsigned short* __restrict__ xTh, const float* __restrict__ bias,
        float* __restrict__ out, int n_out) {
    __shared__ __align__(16) char smem_raw[CHUNK * sizeof(uint2)];  // 16 KB: raw, then tile
    __shared__ __align__(16) char smem_srt[CHUNK * sizeof(uint2)];  // 16 KB
    __shared__ int jhw[8 * TJ];            // per-wave hist -> per-wave cursor
    __shared__ int joff[TJ], jend[TJ];
    uint2* raw = (uint2*)smem_raw;
    uint2* srt = (uint2*)smem_srt;
    float (*tile)[34] = (float (*)[34])smem_raw;   // alias: raw dead after loop

    int c = blockIdx.x;
    int j0 = c << TJ_LOG;
    int tid = threadIdx.x;
    int wv = tid >> 6, lane = tid & 63;
    int q = lane >> 4;               // edge parity 0..3
    int p = lane & 15;               // column pair: cols 2p, 2p+1
    int k0 = wv * 8;                 // 8 waves x 8 j's

    float acc0[8], acc1[8];
#pragma unroll
    for (int k = 0; k < 8; ++k) { acc0[k] = 0.0f; acc1[k] = 0.0f; }

    int pos = c * caps;
    int end = cur[c];
    int cap_end = pos + caps;
    if (end > cap_end) end = cap_end;
    while (pos < end) {
        int n = min(CHUNK, end - pos);
        // 1) zero per-wave hists; fused load + stage + per-wave histogram
        for (int i = tid; i < 8 * TJ; i += GT) jhw[i] = 0;
        __syncthreads();
        for (int i = tid; i < n; i += GT) {
            uint2 r = binA[pos + i];
            raw[i] = r;
            atomicAdd(&jhw[(wv << TJ_LOG) + (r.x >> PACK_SHIFT)], 1);
        }
        __syncthreads();
        // 2) lane k: per-wave bases + exclusive scan over 64 bins
        if (tid < 64) {
            int basew[8];
            int tot = 0;
#pragma unroll
            for (int w = 0; w < 8; ++w) { basew[w] = tot; tot += jhw[(w << TJ_LOG) + tid]; }
            int inc = tot;
            for (int d = 1; d < 64; d <<= 1) {
                int t = __shfl_up(inc, d, 64);
                if (lane >= d) inc += t;
            }
            int off = inc - tot;
            joff[tid] = off;
            jend[tid] = off + tot;
#pragma unroll
            for (int w = 0; w < 8; ++w) jhw[(w << TJ_LOG) + tid] = off + basew[w];
        }
        __syncthreads();
        // 3) scatter raw -> srt into per-wave disjoint regions (intra-wave atomics only)
        for (int i = tid; i < n; i += GT) {
            uint2 r = raw[i];
            int jl = (int)(r.x >> PACK_SHIFT);
            int pcur = atomicAdd(&jhw[(wv << TJ_LOG) + jl], 1);
            srt[pcur] = r;
        }
        __syncthreads();
        // 4) per-k walk: 4 records per wave-instruction, 2 cols per lane, 2x unroll
#pragma unroll
        for (int k = 0; k < 8; ++k) {
            int kk = k0 + k;
            int t = joff[kk] + q;
            int t1 = jend[kk];
            float a0 = 0.0f, a1 = 0.0f;
            for (; t + 4 < t1; t += 8) {
                uint2 r0 = srt[t];
                uint2 r1 = srt[t + 4];
                unsigned u0 = *(const unsigned*)(xTh + (((int)(r0.x & SRC_MASK)) << 5) + (p << 1));
                unsigned u1 = *(const unsigned*)(xTh + (((int)(r1.x & SRC_MASK)) << 5) + (p << 1));
                float v0 = __uint_as_float(r0.y);
                float v1 = __uint_as_float(r1.y);
                a0 += v0 * __uint_as_float(u0 << 16);
                a1 += v0 * __uint_as_float(u0 & 0xFFFF0000u);
                a0 += v1 * __uint_as_float(u1 << 16);
                a1 += v1 * __uint_as_float(u1 & 0xFFFF0000u);
            }
            for (; t < t1; t += 4) {
                uint2 r = srt[t];
                unsigned u = *(const unsigned*)(xTh + (((int)(r.x & SRC_MASK)) << 5) + (p << 1));
                float v = __uint_as_float(r.y);
                a0 += v * __uint_as_float(u << 16);
                a1 += v * __uint_as_float(u & 0xFFFF0000u);
            }
            acc0[k] += a0;
            acc1[k] += a1;
        }
        __syncthreads();   // raw/srt/jhw dead after this point in the iteration
        pos += n;
    }

    // epilogue: combine 4 quarters, write tile (aliases raw)
#pragma unroll
    for (int k = 0; k < 8; ++k) {
        float a0 = acc0[k];
        a0 += __shfl_xor(a0, 16);
        a0 += __shfl_xor(a0, 32);
        float a1 = acc1[k];
        a1 += __shfl_xor(a1, 16);
        a1 += __shfl_xor(a1, 32);
        if (q == 0) {
            tile[k0 + k][(p << 1)]     = a0;
            tile[k0 + k][(p << 1) + 1] = a1;
        }
    }
    __syncthreads();
    for (int i = tid; i < TJ * 32; i += GT) {
        int bb = i >> TJ_LOG;
        int jl = i & (TJ - 1);
        int j = j0 + jl;
        if (j < n_out) out[bb * n_out + j] = tile[jl][bb] + bias[j];
    }
}

// ---------- fixup: add overflow records atomically (normally zero work) ----------
__global__ void fixup_kernel(const uint4* __restrict__ ovf, const int* __restrict__ ovf_cnt,
                             const unsigned short* __restrict__ xTh,
                             float* __restrict__ out, int n_out) {
    int cnt = *ovf_cnt;
    if (cnt > OVF_CAP) cnt = OVF_CAP;
    int total = cnt * 32;
    int tid = blockIdx.x * blockDim.x + threadIdx.x;
    int nth = gridDim.x * blockDim.x;
    for (int i = tid; i < total; i += nth) {
        uint4 r = ovf[i >> 5];
        int b = i & 31;
        float xv = __uint_as_float((unsigned)xTh[(r.x << 5) + b] << 16);
        atomicAdd(&out[(long)b * n_out + (int)r.y], __uint_as_float(r.z) * xv);
    }
}

// ================= fallback (round-1 path, proven; f32 xT) =================
__global__ void xpose_in_f32_kernel(const float* __restrict__ x, float* __restrict__ xT, int N) {
    __shared__ float tile[32][33];
    int n0 = blockIdx.x * 32;
    int tx = threadIdx.x;
    int ty = threadIdx.y;
    if (n0 + tx < N) tile[ty][tx] = x[ty * (long)N + n0 + tx];
    __syncthreads();
    if (n0 + ty < N) xT[(long)(n0 + ty) * 32 + tx] = tile[tx][ty];
}

__global__ void edge_kernel(const float* __restrict__ xT, const float* __restrict__ values,
                            const int* __restrict__ src, const int* __restrict__ dst,
                            float* __restrict__ accT, int nnz) {
    int tid = blockIdx.x * blockDim.x + threadIdx.x;
    int lane_b = tid & 31;
    int e0 = tid >> 5;
    int estride = (gridDim.x * blockDim.x) >> 5;
    for (int e = e0; e < nnz; e += estride) {
        atomicAdd(&accT[(long)dst[e] * 32 + lane_b], values[e] * xT[(long)src[e] * 32 + lane_b]);
    }
}

__global__ void xpose_out_kernel(const float* __restrict__ accT, const float* __restrict__ bias,
                                 float* __restrict__ out, int N) {
    __shared__ float tile[32][33];
    int j0 = blockIdx.x * 32;
    int tx = threadIdx.x;
    int ty = threadIdx.y;
    if (j0 + ty < N) tile[ty][tx] = accT[(long)(j0 + ty) * 32 + tx];
    __syncthreads();
    if (j0 + tx < N) out[ty * (long)N + j0 + tx] = tile[tx][ty] + bias[j0 + tx];
}

__global__ void edge_direct_kernel(const float* __restrict__ x, const float* __restrict__ values,
                                   const int* __restrict__ src, const int* __restrict__ dst,
                                   float* __restrict__ out, int nnz, int N_IN, int N_OUT) {
    int tid = blockIdx.x * blockDim.x + threadIdx.x;
    int lane_b = tid & 31;
    int e0 = tid >> 5;
    int estride = (gridDim.x * blockDim.x) >> 5;
    for (int e = e0; e < nnz; e += estride) {
        atomicAdd(&out[(long)lane_b * N_OUT + dst[e]],
                  values[e] * x[(long)lane_b * N_IN + src[e]]);
    }
}

__global__ void init_out_bias_kernel(float* __restrict__ out, const float* __restrict__ bias,
                                     int N_OUT, int B) {
    long i = (long)blockIdx.x * blockDim.x + threadIdx.x;
    if (i < (long)N_OUT * B) out[i] = bias[i % N_OUT];
}

extern "C" void kernel_launch(void* const* d_in, const int* in_sizes, int n_in,
                              void* d_out, int out_size, void* d_ws, size_t ws_size,
                              hipStream_t stream) {
    const float* x      = (const float*)d_in[0];
    const float* values = (const float*)d_in[1];
    const float* bias   = (const float*)d_in[2];
    const int*   idx    = (const int*)d_in[3];

    const int NNZ   = in_sizes[1];
    const int N_OUT = in_sizes[2];
    const int B     = out_size / N_OUT;
    const int N_IN  = in_sizes[0] / B;

    const int* src = idx;
    const int* dst = idx + NNZ;
    float* out = (float*)d_out;

    const int nsb = (N_OUT + TJ - 1) >> TJ_LOG;

    // fixed bucket capacity: mean + ~8.5 sigma slack, rounded to 8
    int caps = (NNZ + nsb - 1) / nsb + 384;
    caps = (caps + 7) & ~7;

    const size_t xTh_b  = (((size_t)N_IN * 32 * sizeof(unsigned short)) + 15) & ~(size_t)15;
    const size_t bin_b  = (size_t)nsb * caps * sizeof(uint2);
    const size_t cur_b  = (((size_t)nsb * sizeof(int)) + 15) & ~(size_t)15;
    const size_t ovf_b  = (size_t)OVF_CAP * sizeof(uint4);
    const size_t need   = xTh_b + bin_b + cur_b + ovf_b + 16;

    const bool shape_ok = (B == 32) && (NNZ > 0) && (nsb <= NSB_MAX) &&
                          (N_IN <= (1 << PACK_SHIFT));

    if (shape_ok && ws_size >= need) {
        char* p = (char*)d_ws;
        unsigned short* xTh = (unsigned short*)p;  p += xTh_b;
        uint2* binA = (uint2*)p;                   p += bin_b;
        int* cur = (int*)p;                        p += cur_b;
        uint4* ovf = (uint4*)p;                    p += ovf_b;
        int* ovf_cnt = (int*)p;

        {
            dim3 blk(32, 32);
            xpose_in_kernel<<<(N_IN + 31) / 32, blk, 0, stream>>>(x, xTh, N_IN);
        }
        init_cur_kernel<<<(nsb + 255) / 256, 256, 0, stream>>>(cur, ovf_cnt, nsb, caps);
        {
            int nblk = (NNZ + A1_BATCH - 1) / A1_BATCH;
            if (nblk > 1024) nblk = 1024;
            if (nblk < 1) nblk = 1;
            partition_kernel<<<nblk, A1_THREADS, 0, stream>>>(src, dst, values, cur, binA,
                                                              ovf, ovf_cnt, NNZ, nsb, caps);
        }
        gather_sort_kernel<<<nsb, GT, 0, stream>>>(binA, cur, caps, xTh, bias, out, N_OUT);
        fixup_kernel<<<64, 256, 0, stream>>>(ovf, ovf_cnt, xTh, out, N_OUT);
    } else if (B == 32 && ws_size >= (size_t)N_IN * 32 * sizeof(float) +
                                     (size_t)N_OUT * 32 * sizeof(float)) {
        float* xT = (float*)d_ws;
        float* accT = (float*)((char*)d_ws + (size_t)N_IN * 32 * sizeof(float));
        dim3 blk(32, 32);
        xpose_in_f32_kernel<<<(N_IN + 31) / 32, blk, 0, stream>>>(x, xT, N_IN);
        hipMemsetAsync(accT, 0, (size_t)N_OUT * 32 * sizeof(float), stream);
        edge_kernel<<<4096, 256, 0, stream>>>(xT, values, src, dst, accT, NNZ);
        xpose_out_kernel<<<(N_OUT + 31) / 32, blk, 0, stream>>>(accT, bias, out, N_OUT);
    } else {
        long total = (long)N_OUT * B;
        init_out_bias_kernel<<<(int)((total + 255) / 256), 256, 0, stream>>>(out, bias, N_OUT, B);
        edge_direct_kernel<<<4096, 256, 0, stream>>>(x, values, src, dst, out, NNZ, N_IN, N_OUT);
    }
}

// Round 17
// 132.948 us; speedup vs baseline: 1.0232x; 1.0232x over previous
//
#include <hip/hip_runtime.h>

// SparseLinear: out[b, j] = sum_{e: dst[e]==j} values[e] * x[b, src[e]] + bias[j]
// Inputs: x f32 (B,N_IN,1) | values f32 (NNZ,) | bias f32 (N_OUT,1)
//         indices i32 (2,NNZ) row0=src row1=dst | n_out scalar
// Output: f32 (B, N_OUT, 1)
//
// Round-17: gather single-buffer. raw[] staging dropped (binA read twice:
// hist pass + scatter pass, second read L2-hot); CHUNK=4096 >= caps so the
// chunk loop runs once per bucket (no second pass, 4 fewer barriers, no
// LDS round-trip through raw). Partition = r16 stage-less. Walk = r15.

#define TJ 64
#define TJ_LOG 6
#define PACK_SHIFT 17          // src in bits [0,17), jl=dst&63 in [17,23)
#define SRC_MASK ((1u << PACK_SHIFT) - 1u)
#define NSB_MAX 1600
#define CAP 32                 // slot threshold per bucket per round
#define A1_THREADS 512
#define A1_PER_THREAD 8
#define A1_BATCH (A1_THREADS * A1_PER_THREAD)   // 4096
#define CHUNK 4096             // gather records per LDS chunk (>= caps -> 1 pass)
#define GT 512                 // gather threads (8 waves)
#define OVF_CAP 65536          // overflow records (1 MB)

__device__ __forceinline__ unsigned short f32_to_bf16_rn(float f) {
    unsigned u = __float_as_uint(f);
    unsigned r = (u + 0x7FFFu + ((u >> 16) & 1u)) >> 16;
    return (unsigned short)r;
}

// ---------- transpose x (B=32, N) -> xTh (N, 32) bf16 ----------
__global__ void xpose_in_kernel(const float* __restrict__ x, unsigned short* __restrict__ xTh,
                                int N) {
    __shared__ float tile[32][33];
    int n0 = blockIdx.x * 32;
    int tx = threadIdx.x;
    int ty = threadIdx.y;
    if (n0 + tx < N) tile[ty][tx] = x[ty * (long)N + n0 + tx];
    __syncthreads();
    if (n0 + ty < N) xTh[(long)(n0 + ty) * 32 + tx] = f32_to_bf16_rn(tile[tx][ty]);
}

// ---------- init cursors: cur[c] = c*caps; ovf_cnt = 0 ----------
__global__ void init_cur_kernel(int* __restrict__ cur, int* __restrict__ ovf_cnt,
                                int nsb, int caps) {
    int i = blockIdx.x * blockDim.x + threadIdx.x;
    if (i < nsb) cur[i] = i * caps;
    if (i == 0) *ovf_cnt = 0;
}

// ---------- partition: stage-less, records in registers, owner-stores ----------
__global__ __launch_bounds__(A1_THREADS) void partition_kernel(
        const int* __restrict__ src, const int* __restrict__ dst,
        const float* __restrict__ val, int* __restrict__ cur,
        uint2* __restrict__ binA, uint4* __restrict__ ovf, int* __restrict__ ovf_cnt,
        int nnz, int nsb, int caps) {
    __shared__ int scount[NSB_MAX];   // 6.4 KB
    __shared__ int sbase[NSB_MAX];    // 6.4 KB
    for (int i = threadIdx.x; i < nsb; i += A1_THREADS) scount[i] = 0;
    __syncthreads();

    for (long base = (long)blockIdx.x * A1_BATCH; base < nnz;
         base += (long)gridDim.x * A1_BATCH) {
        uint2 rec[A1_PER_THREAD];
        int bkt[A1_PER_THREAD];
        int st[A1_PER_THREAD];       // -2 none/done, -1 pending, >=0 slot this round
#pragma unroll
        for (int q = 0; q < A1_PER_THREAD; ++q) st[q] = -2;

        int e0 = (int)base + threadIdx.x * A1_PER_THREAD;
        if (e0 < nnz) {
            if (e0 + A1_PER_THREAD <= nnz) {
                const int4* s4 = (const int4*)(src + e0);
                const int4* d4 = (const int4*)(dst + e0);
                const float4* v4 = (const float4*)(val + e0);
                int4 sa = s4[0], sb = s4[1];
                int4 da = d4[0], db = d4[1];
                float4 va = v4[0], vb = v4[1];
                int ss[8] = {sa.x, sa.y, sa.z, sa.w, sb.x, sb.y, sb.z, sb.w};
                int dd[8] = {da.x, da.y, da.z, da.w, db.x, db.y, db.z, db.w};
                float vv[8] = {va.x, va.y, va.z, va.w, vb.x, vb.y, vb.z, vb.w};
#pragma unroll
                for (int q = 0; q < 8; ++q) {
                    rec[q] = make_uint2((unsigned)ss[q] | ((unsigned)(dd[q] & (TJ - 1)) << PACK_SHIFT),
                                        __float_as_uint(vv[q]));
                    bkt[q] = dd[q] >> TJ_LOG;
                    st[q] = -1;
                }
            } else {
#pragma unroll
                for (int q = 0; q < 8; ++q) {
                    int e = e0 + q;
                    if (e < nnz) {
                        int d = dst[e];
                        rec[q] = make_uint2((unsigned)src[e] | ((unsigned)(d & (TJ - 1)) << PACK_SHIFT),
                                            __float_as_uint(val[e]));
                        bkt[q] = d >> TJ_LOG;
                        st[q] = -1;
                    }
                }
            }
        }

        while (true) {
            // A) claim slots (records stay in registers)
#pragma unroll
            for (int q = 0; q < A1_PER_THREAD; ++q) {
                if (st[q] == -1) {
                    int s = atomicAdd(&scount[bkt[q]], 1);
                    if (s < CAP) st[q] = s;
                }
            }
            __syncthreads();
            // B) publish global bases, one cur-atomic per touched bucket; reset scount
            for (int t = threadIdx.x; t < nsb; t += A1_THREADS) {
                int cc = scount[t];
                if (cc > 0) {
                    if (cc > CAP) cc = CAP;
                    sbase[t] = atomicAdd(&cur[t], cc);
                    scount[t] = 0;
                }
            }
            __syncthreads();
            // C) owner stores; per-record capacity check spills to ovf
            int rem = 0;
#pragma unroll
            for (int q = 0; q < A1_PER_THREAD; ++q) {
                if (st[q] >= 0) {
                    int g = sbase[bkt[q]] + st[q];
                    if (g < (bkt[q] + 1) * caps) {
                        binA[g] = rec[q];
                    } else {
                        int ob = atomicAdd(ovf_cnt, 1);
                        if (ob < OVF_CAP) {
                            ovf[ob] = make_uint4(rec[q].x & SRC_MASK,
                                                 (unsigned)(bkt[q] * TJ) + (rec[q].x >> PACK_SHIFT),
                                                 rec[q].y, 0u);
                        }
                    }
                    st[q] = -2;
                } else if (st[q] == -1) {
                    ++rem;   // failed slot claim -> retry round
                }
            }
            if (__syncthreads_count(rem) == 0) break;
        }
    }
}

// ---------- gather_sort: single-buffer, 1 pass, 4-edge/instr walk ----------
__global__ __launch_bounds__(GT) void gather_sort_kernel(
        const uint2* __restrict__ binA, const int* __restrict__ cur, int caps,
        const unsigned short* __restrict__ xTh, const float* __restrict__ bias,
        float* __restrict__ out, int n_out) {
    __shared__ __align__(16) char smem_srt[CHUNK * sizeof(uint2)];  // 32 KB: srt, then tile
    __shared__ int jhw[8 * TJ];            // per-wave hist -> per-wave cursor
    __shared__ int joff[TJ], jend[TJ];
    uint2* srt = (uint2*)smem_srt;
    float (*tile)[34] = (float (*)[34])smem_srt;   // alias: srt dead after walk

    int c = blockIdx.x;
    int j0 = c << TJ_LOG;
    int tid = threadIdx.x;
    int wv = tid >> 6, lane = tid & 63;
    int q = lane >> 4;               // edge parity 0..3
    int p = lane & 15;               // column pair: cols 2p, 2p+1
    int k0 = wv * 8;                 // 8 waves x 8 j's

    float acc0[8], acc1[8];
#pragma unroll
    for (int k = 0; k < 8; ++k) { acc0[k] = 0.0f; acc1[k] = 0.0f; }

    int pos = c * caps;
    int end = cur[c];
    int cap_end = pos + caps;
    if (end > cap_end) end = cap_end;
    while (pos < end) {
        int n = min(CHUNK, end - pos);
        // 1) zero per-wave hists; histogram pass (stream binA from global)
        for (int i = tid; i < 8 * TJ; i += GT) jhw[i] = 0;
        __syncthreads();
        for (int i = tid; i < n; i += GT) {
            atomicAdd(&jhw[(wv << TJ_LOG) + (binA[pos + i].x >> PACK_SHIFT)], 1);
        }
        __syncthreads();
        // 2) lane k: per-wave bases + exclusive scan over 64 bins
        if (tid < 64) {
            int basew[8];
            int tot = 0;
#pragma unroll
            for (int w = 0; w < 8; ++w) { basew[w] = tot; tot += jhw[(w << TJ_LOG) + tid]; }
            int inc = tot;
            for (int d = 1; d < 64; d <<= 1) {
                int t = __shfl_up(inc, d, 64);
                if (lane >= d) inc += t;
            }
            int off = inc - tot;
            joff[tid] = off;
            jend[tid] = off + tot;
#pragma unroll
            for (int w = 0; w < 8; ++w) jhw[(w << TJ_LOG) + tid] = off + basew[w];
        }
        __syncthreads();
        // 3) scatter pass: re-read binA (L2-hot) -> srt, per-wave disjoint regions
        for (int i = tid; i < n; i += GT) {
            uint2 r = binA[pos + i];
            int jl = (int)(r.x >> PACK_SHIFT);
            int pcur = atomicAdd(&jhw[(wv << TJ_LOG) + jl], 1);
            srt[pcur] = r;
        }
        __syncthreads();
        // 4) per-k walk: 4 records per wave-instruction, 2 cols per lane, 2x unroll
#pragma unroll
        for (int k = 0; k < 8; ++k) {
            int kk = k0 + k;
            int t = joff[kk] + q;
            int t1 = jend[kk];
            float a0 = 0.0f, a1 = 0.0f;
            for (; t + 4 < t1; t += 8) {
                uint2 r0 = srt[t];
                uint2 r1 = srt[t + 4];
                unsigned u0 = *(const unsigned*)(xTh + (((int)(r0.x & SRC_MASK)) << 5) + (p << 1));
                unsigned u1 = *(const unsigned*)(xTh + (((int)(r1.x & SRC_MASK)) << 5) + (p << 1));
                float v0 = __uint_as_float(r0.y);
                float v1 = __uint_as_float(r1.y);
                a0 += v0 * __uint_as_float(u0 << 16);
                a1 += v0 * __uint_as_float(u0 & 0xFFFF0000u);
                a0 += v1 * __uint_as_float(u1 << 16);
                a1 += v1 * __uint_as_float(u1 & 0xFFFF0000u);
            }
            for (; t < t1; t += 4) {
                uint2 r = srt[t];
                unsigned u = *(const unsigned*)(xTh + (((int)(r.x & SRC_MASK)) << 5) + (p << 1));
                float v = __uint_as_float(r.y);
                a0 += v * __uint_as_float(u << 16);
                a1 += v * __uint_as_float(u & 0xFFFF0000u);
            }
            acc0[k] += a0;
            acc1[k] += a1;
        }
        __syncthreads();   // srt/jhw dead after this point in the iteration
        pos += n;
    }

    // epilogue: combine 4 quarters, write tile (aliases srt)
#pragma unroll
    for (int k = 0; k < 8; ++k) {
        float a0 = acc0[k];
        a0 += __shfl_xor(a0, 16);
        a0 += __shfl_xor(a0, 32);
        float a1 = acc1[k];
        a1 += __shfl_xor(a1, 16);
        a1 += __shfl_xor(a1, 32);
        if (q == 0) {
            tile[k0 + k][(p << 1)]     = a0;
            tile[k0 + k][(p << 1) + 1] = a1;
        }
    }
    __syncthreads();
    for (int i = tid; i < TJ * 32; i += GT) {
        int bb = i >> TJ_LOG;
        int jl = i & (TJ - 1);
        int j = j0 + jl;
        if (j < n_out) out[bb * n_out + j] = tile[jl][bb] + bias[j];
    }
}

// ---------- fixup: add overflow records atomically (normally zero work) ----------
__global__ void fixup_kernel(const uint4* __restrict__ ovf, const int* __restrict__ ovf_cnt,
                             const unsigned short* __restrict__ xTh,
                             float* __restrict__ out, int n_out) {
    int cnt = *ovf_cnt;
    if (cnt > OVF_CAP) cnt = OVF_CAP;
    int total = cnt * 32;
    int tid = blockIdx.x * blockDim.x + threadIdx.x;
    int nth = gridDim.x * blockDim.x;
    for (int i = tid; i < total; i += nth) {
        uint4 r = ovf[i >> 5];
        int b = i & 31;
        float xv = __uint_as_float((unsigned)xTh[(r.x << 5) + b] << 16);
        atomicAdd(&out[(long)b * n_out + (int)r.y], __uint_as_float(r.z) * xv);
    }
}

// ================= fallback (round-1 path, proven; f32 xT) =================
__global__ void xpose_in_f32_kernel(const float* __restrict__ x, float* __restrict__ xT, int N) {
    __shared__ float tile[32][33];
    int n0 = blockIdx.x * 32;
    int tx = threadIdx.x;
    int ty = threadIdx.y;
    if (n0 + tx < N) tile[ty][tx] = x[ty * (long)N + n0 + tx];
    __syncthreads();
    if (n0 + ty < N) xT[(long)(n0 + ty) * 32 + tx] = tile[tx][ty];
}

__global__ void edge_kernel(const float* __restrict__ xT, const float* __restrict__ values,
                            const int* __restrict__ src, const int* __restrict__ dst,
                            float* __restrict__ accT, int nnz) {
    int tid = blockIdx.x * blockDim.x + threadIdx.x;
    int lane_b = tid & 31;
    int e0 = tid >> 5;
    int estride = (gridDim.x * blockDim.x) >> 5;
    for (int e = e0; e < nnz; e += estride) {
        atomicAdd(&accT[(long)dst[e] * 32 + lane_b], values[e] * xT[(long)src[e] * 32 + lane_b]);
    }
}

__global__ void xpose_out_kernel(const float* __restrict__ accT, const float* __restrict__ bias,
                                 float* __restrict__ out, int N) {
    __shared__ float tile[32][33];
    int j0 = blockIdx.x * 32;
    int tx = threadIdx.x;
    int ty = threadIdx.y;
    if (j0 + ty < N) tile[ty][tx] = accT[(long)(j0 + ty) * 32 + tx];
    __syncthreads();
    if (j0 + tx < N) out[ty * (long)N + j0 + tx] = tile[tx][ty] + bias[j0 + tx];
}

__global__ void edge_direct_kernel(const float* __restrict__ x, const float* __restrict__ values,
                                   const int* __restrict__ src, const int* __restrict__ dst,
                                   float* __restrict__ out, int nnz, int N_IN, int N_OUT) {
    int tid = blockIdx.x * blockDim.x + threadIdx.x;
    int lane_b = tid & 31;
    int e0 = tid >> 5;
    int estride = (gridDim.x * blockDim.x) >> 5;
    for (int e = e0; e < nnz; e += estride) {
        atomicAdd(&out[(long)lane_b * N_OUT + dst[e]],
                  values[e] * x[(long)lane_b * N_IN + src[e]]);
    }
}

__global__ void init_out_bias_kernel(float* __restrict__ out, const float* __restrict__ bias,
                                     int N_OUT, int B) {
    long i = (long)blockIdx.x * blockDim.x + threadIdx.x;
    if (i < (long)N_OUT * B) out[i] = bias[i % N_OUT];
}

extern "C" void kernel_launch(void* const* d_in, const int* in_sizes, int n_in,
                              void* d_out, int out_size, void* d_ws, size_t ws_size,
                              hipStream_t stream) {
    const float* x      = (const float*)d_in[0];
    const float* values = (const float*)d_in[1];
    const float* bias   = (const float*)d_in[2];
    const int*   idx    = (const int*)d_in[3];

    const int NNZ   = in_sizes[1];
    const int N_OUT = in_sizes[2];
    const int B     = out_size / N_OUT;
    const int N_IN  = in_sizes[0] / B;

    const int* src = idx;
    const int* dst = idx + NNZ;
    float* out = (float*)d_out;

    const int nsb = (N_OUT + TJ - 1) >> TJ_LOG;

    // fixed bucket capacity: mean + ~8.5 sigma slack, rounded to 8
    int caps = (NNZ + nsb - 1) / nsb + 384;
    caps = (caps + 7) & ~7;

    const size_t xTh_b  = (((size_t)N_IN * 32 * sizeof(unsigned short)) + 15) & ~(size_t)15;
    const size_t bin_b  = (size_t)nsb * caps * sizeof(uint2);
    const size_t cur_b  = (((size_t)nsb * sizeof(int)) + 15) & ~(size_t)15;
    const size_t ovf_b  = (size_t)OVF_CAP * sizeof(uint4);
    const size_t need   = xTh_b + bin_b + cur_b + ovf_b + 16;

    const bool shape_ok = (B == 32) && (NNZ > 0) && (nsb <= NSB_MAX) &&
                          (N_IN <= (1 << PACK_SHIFT));

    if (shape_ok && ws_size >= need) {
        char* p = (char*)d_ws;
        unsigned short* xTh = (unsigned short*)p;  p += xTh_b;
        uint2* binA = (uint2*)p;                   p += bin_b;
        int* cur = (int*)p;                        p += cur_b;
        uint4* ovf = (uint4*)p;                    p += ovf_b;
        int* ovf_cnt = (int*)p;

        {
            dim3 blk(32, 32);
            xpose_in_kernel<<<(N_IN + 31) / 32, blk, 0, stream>>>(x, xTh, N_IN);
        }
        init_cur_kernel<<<(nsb + 255) / 256, 256, 0, stream>>>(cur, ovf_cnt, nsb, caps);
        {
            int nblk = (NNZ + A1_BATCH - 1) / A1_BATCH;
            if (nblk > 1024) nblk = 1024;
            if (nblk < 1) nblk = 1;
            partition_kernel<<<nblk, A1_THREADS, 0, stream>>>(src, dst, values, cur, binA,
                                                              ovf, ovf_cnt, NNZ, nsb, caps);
        }
        gather_sort_kernel<<<nsb, GT, 0, stream>>>(binA, cur, caps, xTh, bias, out, N_OUT);
        fixup_kernel<<<64, 256, 0, stream>>>(ovf, ovf_cnt, xTh, out, N_OUT);
    } else if (B == 32 && ws_size >= (size_t)N_IN * 32 * sizeof(float) +
                                     (size_t)N_OUT * 32 * sizeof(float)) {
        float* xT = (float*)d_ws;
        float* accT = (float*)((char*)d_ws + (size_t)N_IN * 32 * sizeof(float));
        dim3 blk(32, 32);
        xpose_in_f32_kernel<<<(N_IN + 31) / 32, blk, 0, stream>>>(x, xT, N_IN);
        hipMemsetAsync(accT, 0, (size_t)N_OUT * 32 * sizeof(float), stream);
        edge_kernel<<<4096, 256, 0, stream>>>(xT, values, src, dst, accT, NNZ);
        xpose_out_kernel<<<(N_OUT + 31) / 32, blk, 0, stream>>>(accT, bias, out, N_OUT);
    } else {
        long total = (long)N_OUT * B;
        init_out_bias_kernel<<<(int)((total + 255) / 256), 256, 0, stream>>>(out, bias, N_OUT, B);
        edge_direct_kernel<<<4096, 256, 0, stream>>>(x, values, src, dst, out, NNZ, N_IN, N_OUT);
    }
}